// Round 16
// baseline (183.847 us; speedup 1.0000x reference)
//
#include <hip/hip_runtime.h>
#include <hip/hip_cooperative_groups.h>

namespace cg = cooperative_groups;

#define N 8192
#define D 64
#define NB 256                    // fused grid; 1 block/CU -> co-resident
#define SLICE (D * D + D)         // 4160 floats per partial (G then t)
#define SLICE4 (SLICE / 4)        // 1040 float4s
#define PF 64                     // fallback partial count

// ---------------------------------------------------------------------------
// Fused cooperative kernel: P1 partial Gram -> P2 tree reduce -> P3 apply
// ---------------------------------------------------------------------------
__global__ __launch_bounds__(256) void fused_kernel(const float* __restrict__ S,
                                                    float* __restrict__ ws,
                                                    float* __restrict__ out) {
    cg::grid_group grid = cg::this_grid();
    const int tid = threadIdx.x;
    const int bid = blockIdx.x;

    // ---------------- Phase 1: partial Gram, register-tiled ----------------
    {
        const int ty = tid >> 4;             // 0..15
        const int tx = tid & 15;             // 0..15
        float acc[4][4];
#pragma unroll
        for (int i = 0; i < 4; ++i)
#pragma unroll
            for (int j = 0; j < 4; ++j) acc[i][j] = 0.f;
        float tac[4] = {0.f, 0.f, 0.f, 0.f};

        const int rpb = N / NB;              // 32 rows per block
        const float* Sa = S + (size_t)(bid * rpb) * D + 4 * ty;
        const float* Sb = S + (size_t)(bid * rpb) * D + 4 * tx;
#pragma unroll 8
        for (int r = 0; r < rpb; ++r) {
            const float4 a = *(const float4*)(Sa + (size_t)r * D);
            const float4 b = *(const float4*)(Sb + (size_t)r * D);
            const float av[4] = {a.x, a.y, a.z, a.w};
            const float bv[4] = {b.x, b.y, b.z, b.w};
#pragma unroll
            for (int i = 0; i < 4; ++i)
#pragma unroll
                for (int j = 0; j < 4; ++j) acc[i][j] += av[i] * bv[j];
            if (ty == 0) {
#pragma unroll
                for (int j = 0; j < 4; ++j) tac[j] += bv[j];
            }
        }
        float* pw = ws + (size_t)bid * SLICE;
#pragma unroll
        for (int i = 0; i < 4; ++i)
            *(float4*)(pw + (4 * ty + i) * D + 4 * tx) =
                make_float4(acc[i][0], acc[i][1], acc[i][2], acc[i][3]);
        if (ty == 0)
            *(float4*)(pw + D * D + 4 * tx) =
                make_float4(tac[0], tac[1], tac[2], tac[3]);
    }
    __threadfence();
    grid.sync();

    // ------- Phase 2: reduce 256 partials; one wave per float4-column -------
    {
        const float4* src = (const float4*)ws;
        float4* dst = (float4*)(ws + (size_t)NB * SLICE);
        const int w = tid >> 6;              // wave 0..3
        const int lane = tid & 63;
        const int wc0 = bid * 4 + w;         // float4-columns 0..1023

#pragma unroll
        for (int e = 0; e < 2; ++e) {
            const int wc = e ? (1024 + wc0) : wc0;   // e=1: t columns (16 waves)
            if (e && wc0 >= 16) break;
            float4 acc = make_float4(0.f, 0.f, 0.f, 0.f);
#pragma unroll
            for (int q = 0; q < 4; ++q) {    // lane sums partials 4*lane..+3
                const float4 v = src[(size_t)(4 * lane + q) * SLICE4 + wc];
                acc.x += v.x; acc.y += v.y; acc.z += v.z; acc.w += v.w;
            }
#pragma unroll
            for (int s = 1; s < 64; s <<= 1) {
                acc.x += __shfl_xor(acc.x, s, 64);
                acc.y += __shfl_xor(acc.y, s, 64);
                acc.z += __shfl_xor(acc.z, s, 64);
                acc.w += __shfl_xor(acc.w, s, 64);
            }
            if (lane == 0) dst[wc] = acc;
        }
    }
    __threadfence();
    grid.sync();

    // ---------------- Phase 3: apply ----------------
    {
        __shared__ float Gs[D * D];
        __shared__ float ts[D];
        const float* Gf = ws + (size_t)NB * SLICE;
#pragma unroll
        for (int i = tid; i < (D * D) / 4; i += 256)
            ((float4*)Gs)[i] = ((const float4*)Gf)[i];
        if (tid < D) ts[tid] = Gf[D * D + tid];
        __syncthreads();

        const int lane = tid & 63;
        const int w = tid >> 6;
        const float tl = ts[lane];

#pragma unroll
        for (int p = 0; p < 4; ++p) {        // 8 rows/wave as 4 pairs
            const int ia = bid * 32 + w * 8 + 2 * p;
            const int ib = ia + 1;
            const float va = S[(size_t)ia * D + lane];
            const float vb = S[(size_t)ib * D + lane];

            float pa = va * tl, pb = vb * tl;
#pragma unroll
            for (int s = 1; s < 64; s <<= 1) {
                pa += __shfl_xor(pa, s, 64);
                pb += __shfl_xor(pb, s, 64);
            }

            float aa = 0.f, ab = 0.f;
#pragma unroll
            for (int k = 0; k < D; ++k) {
                const float g = Gs[k * D + lane];    // stride-1: conflict-free
                aa += __shfl(va, k, 64) * g;         // constant lane -> readlane
                ab += __shfl(vb, k, 64) * g;
            }
            out[(size_t)ia * D + lane] = aa / pa;
            out[(size_t)ib * D + lane] = ab / pb;
        }
    }
}

// ---------------------------------------------------------------------------
// Fallback (r8-proven 3-kernel structure), used iff cooperative launch fails
// ---------------------------------------------------------------------------
__global__ __launch_bounds__(256) void gram_partial(const float* __restrict__ S,
                                                    float* __restrict__ ws) {
    const int tid = threadIdx.x;
    const int ty = tid >> 4;
    const int tx = tid & 15;

    float acc[4][4];
#pragma unroll
    for (int i = 0; i < 4; ++i)
#pragma unroll
        for (int j = 0; j < 4; ++j) acc[i][j] = 0.f;
    float tac[4] = {0.f, 0.f, 0.f, 0.f};

    const int rpb = N / PF;                  // 128 rows per block
    const int r0 = blockIdx.x * rpb;
    const float* Sa = S + (size_t)r0 * D + 4 * ty;
    const float* Sb = S + (size_t)r0 * D + 4 * tx;

#pragma unroll 8
    for (int r = 0; r < rpb; ++r) {
        const float4 a = *(const float4*)(Sa + (size_t)r * D);
        const float4 b = *(const float4*)(Sb + (size_t)r * D);
        const float av[4] = {a.x, a.y, a.z, a.w};
        const float bv[4] = {b.x, b.y, b.z, b.w};
#pragma unroll
        for (int i = 0; i < 4; ++i)
#pragma unroll
            for (int j = 0; j < 4; ++j) acc[i][j] += av[i] * bv[j];
        if (ty == 0) {
#pragma unroll
            for (int j = 0; j < 4; ++j) tac[j] += bv[j];
        }
    }

    float* pw = ws + (size_t)blockIdx.x * SLICE;
#pragma unroll
    for (int i = 0; i < 4; ++i)
        *(float4*)(pw + (4 * ty + i) * D + 4 * tx) =
            make_float4(acc[i][0], acc[i][1], acc[i][2], acc[i][3]);
    if (ty == 0)
        *(float4*)(pw + D * D + 4 * tx) =
            make_float4(tac[0], tac[1], tac[2], tac[3]);
}

__global__ __launch_bounds__(256) void reduce_kernel(float* __restrict__ ws) {
    const float4* src = (const float4*)ws;
    float4* dst = (float4*)(ws + (size_t)NB * SLICE);   // same final slot as fused
    const int gid = blockIdx.x * 256 + threadIdx.x;
    for (int i4 = gid; i4 < SLICE4; i4 += 1024) {
        float4 acc = make_float4(0.f, 0.f, 0.f, 0.f);
#pragma unroll 8
        for (int p = 0; p < PF; ++p) {
            const float4 v = src[(size_t)p * SLICE4 + i4];
            acc.x += v.x; acc.y += v.y; acc.z += v.z; acc.w += v.w;
        }
        dst[i4] = acc;
    }
}

__global__ __launch_bounds__(256) void apply_kernel(const float* __restrict__ S,
                                                    const float* __restrict__ G,
                                                    const float* __restrict__ t,
                                                    float* __restrict__ out) {
    __shared__ float Gs[D * D];
    __shared__ float ts[D];
    const int tid = threadIdx.x;
#pragma unroll
    for (int i = tid; i < (D * D) / 4; i += 256)
        ((float4*)Gs)[i] = ((const float4*)G)[i];
    if (tid < D) ts[tid] = t[tid];
    __syncthreads();

    const int lane = tid & 63;
    const int wid = tid >> 6;
    const float tl = ts[lane];

    const int ia = (blockIdx.x * 4 + wid) * 2;
    const int ib = ia + 1;
    const float va = S[(size_t)ia * D + lane];
    const float vb = S[(size_t)ib * D + lane];

    float pa = va * tl, pb = vb * tl;
#pragma unroll
    for (int s = 1; s < 64; s <<= 1) {
        pa += __shfl_xor(pa, s, 64);
        pb += __shfl_xor(pb, s, 64);
    }

    float aa = 0.f, ab = 0.f;
#pragma unroll
    for (int k = 0; k < D; ++k) {
        const float g = Gs[k * D + lane];
        aa += __shfl(va, k, 64) * g;
        ab += __shfl(vb, k, 64) * g;
    }
    out[(size_t)ia * D + lane] = aa / pa;
    out[(size_t)ib * D + lane] = ab / pb;
}

extern "C" void kernel_launch(void* const* d_in, const int* in_sizes, int n_in,
                              void* d_out, int out_size, void* d_ws, size_t ws_size,
                              hipStream_t stream) {
    const float* S = (const float*)d_in[0];
    float* out = (float*)d_out;
    float* ws = (float*)d_ws;
    float* Gfin = ws + (size_t)NB * SLICE;
    float* tfin = Gfin + D * D;

    void* args[] = {(void*)&S, (void*)&ws, (void*)&out};
    hipError_t err = hipLaunchCooperativeKernel((const void*)fused_kernel,
                                                dim3(NB), dim3(256), args, 0,
                                                stream);
    if (err != hipSuccess) {
        (void)hipGetLastError();             // clear sticky error
        gram_partial<<<PF, 256, 0, stream>>>(S, ws);
        reduce_kernel<<<4, 256, 0, stream>>>(ws);
        apply_kernel<<<1024, 256, 0, stream>>>(S, Gfin, tfin, out);
    }
}

// Round 17
// 85.300 us; speedup vs baseline: 2.1553x; 2.1553x over previous
//
#include <hip/hip_runtime.h>

#define N 8192
#define D 64
#define P 64                      // number of partial Gram copies
#define SLICE (D * D + D)         // 4160 floats per partial (G then t)
#define SLICE4 (SLICE / 4)        // 1040 float4s

// Kernel 1: per-block partial G = S_blk^T S_blk and t = colsum, register-tiled.
// Thread (ty,tx) owns G[4ty..4ty+3][4tx..4tx+3]. Plain float4 stores to a
// private ws slice — zero atomics, zero cross-block contention.
__global__ __launch_bounds__(256) void gram_partial(const float* __restrict__ S,
                                                    float* __restrict__ ws) {
    const int tid = threadIdx.x;
    const int ty = tid >> 4;                 // 0..15
    const int tx = tid & 15;                 // 0..15

    float acc[4][4];
#pragma unroll
    for (int i = 0; i < 4; ++i)
#pragma unroll
        for (int j = 0; j < 4; ++j) acc[i][j] = 0.f;
    float tac[4] = {0.f, 0.f, 0.f, 0.f};

    const int rpb = N / P;                   // 128 rows per block
    const int r0 = blockIdx.x * rpb;
    const float* Sa = S + (size_t)r0 * D + 4 * ty;
    const float* Sb = S + (size_t)r0 * D + 4 * tx;

#pragma unroll 8
    for (int r = 0; r < rpb; ++r) {
        const float4 a = *(const float4*)(Sa + (size_t)r * D);
        const float4 b = *(const float4*)(Sb + (size_t)r * D);
        const float av[4] = {a.x, a.y, a.z, a.w};
        const float bv[4] = {b.x, b.y, b.z, b.w};
#pragma unroll
        for (int i = 0; i < 4; ++i)
#pragma unroll
            for (int j = 0; j < 4; ++j) acc[i][j] += av[i] * bv[j];
        if (ty == 0) {
#pragma unroll
            for (int j = 0; j < 4; ++j) tac[j] += bv[j];
        }
    }

    float* pw = ws + (size_t)blockIdx.x * SLICE;
#pragma unroll
    for (int i = 0; i < 4; ++i)
        *(float4*)(pw + (4 * ty + i) * D + 4 * tx) =
            make_float4(acc[i][0], acc[i][1], acc[i][2], acc[i][3]);
    if (ty == 0)
        *(float4*)(pw + D * D + 4 * tx) =
            make_float4(tac[0], tac[1], tac[2], tac[3]);
}

// Kernel 2: sum the P partial slices -> final G,t at ws + P*SLICE.
// Thread handles one float4 of the slice; reads coalesced across threads.
__global__ __launch_bounds__(256) void reduce_kernel(float* __restrict__ ws) {
    const float4* src = (const float4*)ws;
    float4* dst = (float4*)(ws + (size_t)P * SLICE);
    const int gid = blockIdx.x * 256 + threadIdx.x;
    for (int i4 = gid; i4 < SLICE4; i4 += 1024) {
        float4 acc = make_float4(0.f, 0.f, 0.f, 0.f);
#pragma unroll 8
        for (int p = 0; p < P; ++p) {
            const float4 v = src[(size_t)p * SLICE4 + i4];
            acc.x += v.x; acc.y += v.y; acc.z += v.z; acc.w += v.w;
        }
        dst[i4] = acc;
    }
}

// Kernel 3: out[i,:] = (s_i @ G) / (s_i . t). One row-pair per wave
// (2 indep FMA chains sharing Gs reads); denominator via 6-step butterfly.
__global__ __launch_bounds__(256) void apply_kernel(const float* __restrict__ S,
                                                    const float* __restrict__ G,
                                                    const float* __restrict__ t,
                                                    float* __restrict__ out) {
    __shared__ float Gs[D * D];
    __shared__ float ts[D];
    const int tid = threadIdx.x;
#pragma unroll
    for (int i = tid; i < (D * D) / 4; i += 256)
        ((float4*)Gs)[i] = ((const float4*)G)[i];
    if (tid < D) ts[tid] = t[tid];
    __syncthreads();

    const int lane = tid & 63;
    const int wid = tid >> 6;
    const float tl = ts[lane];

    const int ia = (blockIdx.x * 4 + wid) * 2;
    const int ib = ia + 1;
    const float va = S[(size_t)ia * D + lane];
    const float vb = S[(size_t)ib * D + lane];

    float pa = va * tl, pb = vb * tl;
#pragma unroll
    for (int s = 1; s < 64; s <<= 1) {
        pa += __shfl_xor(pa, s, 64);
        pb += __shfl_xor(pb, s, 64);
    }

    float aa = 0.f, ab = 0.f;
#pragma unroll
    for (int k = 0; k < D; ++k) {
        const float g = Gs[k * D + lane];             // stride-1: conflict-free
        aa += __shfl(va, k, 64) * g;                  // constant lane -> readlane
        ab += __shfl(vb, k, 64) * g;
    }
    out[(size_t)ia * D + lane] = aa / pa;
    out[(size_t)ib * D + lane] = ab / pb;
}

extern "C" void kernel_launch(void* const* d_in, const int* in_sizes, int n_in,
                              void* d_out, int out_size, void* d_ws, size_t ws_size,
                              hipStream_t stream) {
    const float* S = (const float*)d_in[0];
    float* out = (float*)d_out;
    float* ws = (float*)d_ws;
    float* Gfin = ws + (size_t)P * SLICE;
    float* tfin = Gfin + D * D;

    gram_partial<<<P, 256, 0, stream>>>(S, ws);
    reduce_kernel<<<4, 256, 0, stream>>>(ws);
    apply_kernel<<<1024, 256, 0, stream>>>(S, Gfin, tfin, out);
}